// Round 3
// baseline (37.735 us; speedup 1.0000x reference)
//
#include <hip/hip_runtime.h>

// UserEmbedding: out[b, d] = W[d, x[b]]
//   x: [16384] int32, W: [64, 1_000_000] f32 row-major, out: [16384, 64] f32
//
// Round-2 result: K=8 MLP boost neutral -> memory-path throughput-bound.
// 1M random lines / 26us ~= 50ns/bank = tRC => DRAM row-activation-bound.
// Fix: bucket-sort indices by user id, gather in sorted order with lanes =
// consecutive sorted users so each instruction's 64 reads land in ~8 DRAM
// pages (row hits) instead of 64 random pages. LDS transpose keeps stores
// coalesced (256 B per batch row).

#define NUM_USERS 1000000
#define DIM 64
#define BATCH 16384

#define NB 4096                 // buckets; span = 256 users = 1 KB/row
#define SORT_THREADS 1024
#define EPT (BATCH / SORT_THREADS)      // 16 elements per sort thread
#define BPT (NB / SORT_THREADS)         // 4 buckets per sort thread

#define GBLK 64                 // pairs (users) per gather block
#define GTHREADS 512            // 8 waves; wave w owns d in [w*8, w*8+8)

// --- Kernel 1: single-block LDS counting sort of (u, b) pairs by u>>8 ---
__global__ __launch_bounds__(SORT_THREADS) void UE_sort_kernel(
    const int* __restrict__ x, uint2* __restrict__ pairs) {
    __shared__ unsigned hist[NB];
    __shared__ unsigned bases[NB];
    __shared__ unsigned ssum[SORT_THREADS];
    const int t = threadIdx.x;

    for (int i = t; i < NB; i += SORT_THREADS) hist[i] = 0u;
    __syncthreads();

    int u[EPT];
#pragma unroll
    for (int i = 0; i < EPT; ++i) {
        u[i] = x[i * SORT_THREADS + t];          // coalesced
        atomicAdd(&hist[u[i] >> 8], 1u);
    }
    __syncthreads();

    // two-level exclusive scan over hist[NB]
    unsigned loc[BPT], s = 0;
#pragma unroll
    for (int k = 0; k < BPT; ++k) { loc[k] = hist[t * BPT + k]; s += loc[k]; }
    ssum[t] = s;
    __syncthreads();
    for (int off = 1; off < SORT_THREADS; off <<= 1) {
        unsigned v = ssum[t];
        unsigned w = (t >= off) ? ssum[t - off] : 0u;
        __syncthreads();
        ssum[t] = v + w;
        __syncthreads();
    }
    unsigned base = ssum[t] - s;                 // exclusive prefix
#pragma unroll
    for (int k = 0; k < BPT; ++k) { bases[t * BPT + k] = base; base += loc[k]; }
    __syncthreads();

    // reuse hist as per-bucket cursors
    for (int i = t; i < NB; i += SORT_THREADS) hist[i] = 0u;
    __syncthreads();

#pragma unroll
    for (int i = 0; i < EPT; ++i) {
        const int uu = u[i];
        const int bkt = uu >> 8;
        const unsigned pos = bases[bkt] + atomicAdd(&hist[bkt], 1u);
        pairs[pos] = make_uint2((unsigned)uu, (unsigned)(i * SORT_THREADS + t));
    }
}

// --- Kernel 2: gather in sorted order, lanes = users, LDS transpose ---
__global__ __launch_bounds__(GTHREADS) void UE_gather_kernel(
    const uint2* __restrict__ pairs, const float* __restrict__ W,
    float* __restrict__ out) {
    __shared__ float tile[GBLK][DIM + 1];        // +1 pad: conflict-free
    __shared__ unsigned brow[GBLK];
    const int t = threadIdx.x;
    const int lane = t & 63;
    const int w = t >> 6;                        // 0..7
    const int p0 = blockIdx.x * GBLK;

    const uint2 pr = pairs[p0 + lane];           // all waves load the 64 pairs
    if (t < GBLK) brow[t] = pr.y;
    const size_t u = (size_t)pr.x;

#pragma unroll
    for (int i = 0; i < DIM / 8; ++i) {          // 8 rows per wave
        const int d = w * 8 + i;
        tile[lane][d] = W[(size_t)d * NUM_USERS + u];  // 64 sorted users/instr
    }
    __syncthreads();

#pragma unroll
    for (int i = 0; i < DIM / 8; ++i) {          // 8 pairs per wave
        const int p = w * 8 + i;
        out[(size_t)brow[p] * DIM + lane] = tile[p][lane];  // 256 B contiguous
    }
}

extern "C" void kernel_launch(void* const* d_in, const int* in_sizes, int n_in,
                              void* d_out, int out_size, void* d_ws, size_t ws_size,
                              hipStream_t stream) {
    const int* x = (const int*)d_in[0];
    const float* W = (const float*)d_in[1];
    float* out = (float*)d_out;
    uint2* pairs = (uint2*)d_ws;                 // 16384 * 8 B = 128 KB

    UE_sort_kernel<<<1, SORT_THREADS, 0, stream>>>(x, pairs);
    UE_gather_kernel<<<BATCH / GBLK, GTHREADS, 0, stream>>>(pairs, W, out);
}

// Round 4
// 26.496 us; speedup vs baseline: 1.4242x; 1.4242x over previous
//
#include <hip/hip_runtime.h>

// UserEmbedding: out[b, d] = W[d, x[b]]
//   x: [16384] int32, W: [64, 1_000_000] f32 row-major, out: [16384, 64] f32
//
// Best structure (round 1): one thread per output element, tid = b*64 + d.
// Each 64-lane wave: one broadcast x[b] load, 64 scattered 4B reads of W
// (each its own HBM line — unavoidable: needed users are random, ~1.13
// needed values per 64B line), one fully-coalesced 256B store.
//
// Evidence this is transaction-rate-bound (not fixable at HIP level):
//   - K=8 per-thread MLP: neutral (round 2, 27.6us) — TLP already saturates.
//   - index-sorted gather for DRAM page locality: regression (round 3,
//     37.7us) — access order doesn't move the ceiling.
//   - 1M lines / 26us = 38.5 G tx/s ~= 2.4 TB/s line traffic ~= the
//     expected random-access fraction of the 6.3 TB/s streaming ceiling.
//
// Tweak vs round 1: nontemporal store for out (write-once, never re-read)
// so the 4MB output doesn't displace W lines in L2/LLC across replays.

#define NUM_USERS 1000000
#define DIM 64
#define BATCH 16384

__global__ __launch_bounds__(256) void UserEmbedding_61873298866785_kernel(
    const int* __restrict__ x,
    const float* __restrict__ W,
    float* __restrict__ out) {
    const int tid = blockIdx.x * blockDim.x + threadIdx.x;  // 0 .. BATCH*DIM-1
    const int b = tid >> 6;   // batch element (uniform within a wave)
    const int d = tid & 63;   // embedding dim (lane id)
    const int u = x[b];       // broadcast within the wave
    const float v = W[(size_t)d * NUM_USERS + (size_t)u];
    __builtin_nontemporal_store(v, &out[tid]);
}

extern "C" void kernel_launch(void* const* d_in, const int* in_sizes, int n_in,
                              void* d_out, int out_size, void* d_ws, size_t ws_size,
                              hipStream_t stream) {
    const int* x = (const int*)d_in[0];
    const float* W = (const float*)d_in[1];
    float* out = (float*)d_out;

    const int total = BATCH * DIM;          // 1,048,576
    const int block = 256;
    const int grid = total / block;         // 4096
    UserEmbedding_61873298866785_kernel<<<grid, block, 0, stream>>>(x, W, out);
}